// Round 18
// baseline (1195.428 us; speedup 1.0000x reference)
//
#include <hip/hip_runtime.h>
#include <hip/hip_bf16.h>
#include <stdint.h>

// ---------------- constants ----------------
#define TT 64
#define BB 32
#define NHIDC 768
#define NBK 6
#define BSZ 128
#define NTOKC 32000

using f32x4  = __attribute__((ext_vector_type(4))) float;
using f32x2  = __attribute__((ext_vector_type(2))) float;
using short8 = __attribute__((ext_vector_type(8))) short;
typedef unsigned long long u64;

// ---------------- workspace layout (bytes) ----------------
#define OFF_XPUB  4096u        // [2][16][6][2][132] u64 tagged exchange
#define OFF_WTH   1048576u     // WihT hi bf16 [6][512][512] (3 MB)
#define OFF_WTL   4194304u     // WihT lo bf16 (3 MB)
#define OFF_HTB   8065024u     // [64][32][768] bf16
#define OFF_K1    11210752u    // [64][32][64] f32
#define OFF_V1H   11735040u    // V1 hi bf16 [2048][512] (2 MB)
#define OFF_V1L   13832192u    // V1 lo bf16 (2 MB)
#define OFF_U     15929344u    // [64][32][6][512] f32
#define OFF_WDB   41095168u    // [32000][768] bf16

__device__ __forceinline__ float sigf(float x){ return 1.f/(1.f + expf(-x)); }

// tagged 8B MALL-coherent exchange ops: tag in hi32, f32 value in lo32.
__device__ __forceinline__ void stp(u64* p, float v, unsigned tag){
  union { float f; unsigned u; } cv; cv.f = v;
  const u64 pk = ((u64)tag << 32) | cv.u;
  __hip_atomic_store(p, pk, __ATOMIC_RELAXED, __HIP_MEMORY_SCOPE_AGENT);
}
__device__ __forceinline__ float ldp(const u64* p, unsigned tag){
  u64 v = __hip_atomic_load(p, __ATOMIC_RELAXED, __HIP_MEMORY_SCOPE_AGENT);
  while ((unsigned)(v >> 32) < tag){
    __builtin_amdgcn_s_sleep(1);
    v = __hip_atomic_load(p, __ATOMIC_RELAXED, __HIP_MEMORY_SCOPE_AGENT);
  }
  union { unsigned u; float f; } cv; cv.u = (unsigned)v;
  return cv.f;
}
#define CBAR asm volatile("" ::: "memory")

__device__ __forceinline__ void gload16(const void* g, void* l){
  __builtin_amdgcn_global_load_lds(
      (const __attribute__((address_space(1))) unsigned int*)g,
      (__attribute__((address_space(3))) unsigned int*)l, 16, 0, 0);
}

__device__ __forceinline__ int xslot(int par, int gg, int nn, int b){
  return (((par*16 + gg)*6 + nn)*2 + b)*132;
}

__device__ __forceinline__ void split_hl(float v, unsigned short& h16, unsigned short& l16){
  __hip_bfloat16 h = __float2bfloat16(v);
  float hv = __bfloat162float(h);
  __hip_bfloat16 l = __float2bfloat16(v - hv);
  h16 = *reinterpret_cast<unsigned short*>(&h);
  l16 = *reinterpret_cast<unsigned short*>(&l);
}

// ---------------- shared 256-thread GEMM tile (f32 out, normal stores) ----------------
template<int TM, int TN>
__device__ void gemm_tile(const float* __restrict__ A, int lda,
                          const float* __restrict__ Bb, int ldb,
                          float* __restrict__ Cb, int ldc,
                          int N, int K, int m0, int n0,
                          float* AsP, float* BsP, int tid)
{
  constexpr int BM = 16*TM, BN = 16*TN;
  float (*As)[BM]   = reinterpret_cast<float(*)[BM]>(AsP);
  float (*Bs)[BN+4] = reinterpret_cast<float(*)[BN+4]>(BsP);
  const int tx = tid & 15, ty = tid >> 4;
  float acc[TM][TN];
  #pragma unroll
  for (int i=0;i<TM;++i)
    #pragma unroll
    for (int j=0;j<TN;++j) acc[i][j]=0.f;

  for (int k0=0; k0<K; k0+=16){
    {
      const int r = tid>>2, kk = (tid&3)*4;
      const float4 v0 = *(const float4*)&A[(long)(m0+r)*lda + k0 + kk];
      As[kk+0][r]=v0.x; As[kk+1][r]=v0.y; As[kk+2][r]=v0.z; As[kk+3][r]=v0.w;
    }
    {
      const int rb = tid>>4, cb = (tid&15)*4;
      float4 v0 = {0,0,0,0};
      if (n0+cb+4 <= N) v0 = *(const float4*)&Bb[(long)(k0+rb)*ldb + n0+cb];
      *(float4*)&Bs[rb][cb] = v0;
    }
    __syncthreads();
    #pragma unroll
    for (int kk=0; kk<16; ++kk){
      float av[TM], bv[TN];
      #pragma unroll
      for (int i=0;i<TM;++i) av[i] = As[kk][ty*TM+i];
      #pragma unroll
      for (int j=0;j<TN;++j) bv[j] = Bs[kk][tx*TN+j];
      #pragma unroll
      for (int i=0;i<TM;++i)
        #pragma unroll
        for (int j=0;j<TN;++j) acc[i][j] += av[i]*bv[j];
    }
    __syncthreads();
  }
  #pragma unroll
  for (int i=0;i<TM;++i){
    const int row = m0 + ty*TM + i;
    #pragma unroll
    for (int j=0;j<TN;++j){
      const int col = n0 + tx*TN + j;
      if (col < N) Cb[(long)row*ldc + col] = acc[i][j];
    }
  }
}

// ---------------- V1 GEMM tile with hi/lo bf16 epilogue (TM=TN=4) ----------------
__device__ void gemm_tile_v1(const float* __restrict__ A,
                             const float* __restrict__ Bb,
                             unsigned short* __restrict__ V1H,
                             unsigned short* __restrict__ V1L,
                             int m0, int n0,
                             float* AsP, float* BsP, int tid)
{
  float (*As)[64] = reinterpret_cast<float(*)[64]>(AsP);
  float (*Bs)[68] = reinterpret_cast<float(*)[68]>(BsP);
  const int tx = tid & 15, ty = tid >> 4;
  float acc[4][4];
  #pragma unroll
  for (int i=0;i<4;++i)
    #pragma unroll
    for (int j=0;j<4;++j) acc[i][j]=0.f;

  for (int k0=0; k0<768; k0+=16){
    {
      const int r = tid>>2, kk = (tid&3)*4;
      const float4 v0 = *(const float4*)&A[(long)(m0+r)*768 + k0 + kk];
      As[kk+0][r]=v0.x; As[kk+1][r]=v0.y; As[kk+2][r]=v0.z; As[kk+3][r]=v0.w;
    }
    {
      const int rb = tid>>4, cb = (tid&15)*4;
      const float4 v0 = *(const float4*)&Bb[(long)(k0+rb)*512 + n0+cb];
      *(float4*)&Bs[rb][cb] = v0;
    }
    __syncthreads();
    #pragma unroll
    for (int kk=0; kk<16; ++kk){
      float av[4], bv[4];
      #pragma unroll
      for (int i=0;i<4;++i) av[i] = As[kk][ty*4+i];
      #pragma unroll
      for (int j=0;j<4;++j) bv[j] = Bs[kk][tx*4+j];
      #pragma unroll
      for (int i=0;i<4;++i)
        #pragma unroll
        for (int j=0;j<4;++j) acc[i][j] += av[i]*bv[j];
    }
    __syncthreads();
  }
  #pragma unroll
  for (int i=0;i<4;++i){
    const int row = m0 + ty*4 + i;
    const int col0 = n0 + tx*4;
    ushort4 oh, ol;
    split_hl(acc[i][0], oh.x, ol.x);
    split_hl(acc[i][1], oh.y, ol.y);
    split_hl(acc[i][2], oh.z, ol.z);
    split_hl(acc[i][3], oh.w, ol.w);
    *(ushort4*)&V1H[(long)row*512 + col0] = oh;
    *(ushort4*)&V1L[(long)row*512 + col0] = ol;
  }
}

// ---------------- pre1: K1 || V1(hi/lo) || xpub zero || WihT transpose ----------------
__global__ __launch_bounds__(256) void pre1_kernel(
    const float* __restrict__ x,
    const float* __restrict__ Wk_in, const float* __restrict__ Wv_in,
    const float* __restrict__ Wih,
    float* __restrict__ K1b,
    unsigned short* __restrict__ V1H, unsigned short* __restrict__ V1L,
    unsigned short* __restrict__ WTH, unsigned short* __restrict__ WTL,
    u64* __restrict__ xpub)
{
  __shared__ float As[16*64];
  __shared__ float Bs[16*68];
  __shared__ float T[64][65];
  const int bid = blockIdx.x, tid = threadIdx.x;
  if (bid < 32){
    gemm_tile<4,4>(x, 768, Wk_in + 768*64, 64, K1b, 64, 64, 768,
                   bid*64, 0, As, Bs, tid);
  } else if (bid < 288){
    const int v = bid - 32;
    gemm_tile_v1(x, Wv_in + 768*512, V1H, V1L,
                 (v>>3)*64, (v&7)*64, As, Bs, tid);
  } else if (bid < 352){
    const int nx = 2*16*6*2*132;
    for (int i = (bid-288)*256 + tid; i < nx; i += 64*256)
      __hip_atomic_store(&xpub[i], 0ull, __ATOMIC_RELAXED, __HIP_MEMORY_SCOPE_AGENT);
  } else {
    // WihT[z][c][k] hi/lo: 64x64 LDS-tiled transpose, 384 blocks
    const int tb = bid - 352;
    const int z = tb>>6, tile = tb&63, kt = (tile>>3)<<6, ct = (tile&7)<<6;
    const float* src = Wih + (long)z*262144;
    #pragma unroll 4
    for (int i=0;i<16;++i){
      const int idx = i*256+tid, rr = idx>>6, cc = idx&63;
      T[rr][cc] = src[(long)(kt+rr)*512 + ct+cc];
    }
    __syncthreads();
    #pragma unroll 4
    for (int i=0;i<16;++i){
      const int idx = i*256+tid, cr = idx>>6, kk = idx&63;
      unsigned short h16, l16;
      split_hl(T[kk][cr], h16, l16);
      WTH[(long)z*262144 + (long)(ct+cr)*512 + kt+kk] = h16;
      WTL[(long)z*262144 + (long)(ct+cr)*512 + kt+kk] = l16;
    }
  }
}

// ---------------- pre2: U via split-bf16 MFMA (384 blocks) || Wd cast (384 blocks) ----------------
__global__ __launch_bounds__(256) void pre2_kernel(
    const unsigned short* __restrict__ V1H, const unsigned short* __restrict__ V1L,
    const unsigned short* __restrict__ WTH, const unsigned short* __restrict__ WTL,
    const float* __restrict__ Wd,
    float* __restrict__ Ub, unsigned short* __restrict__ Wdb)
{
  __shared__ unsigned short AH[4096], AL[4096], BH[4096], BL[4096];
  const int bid = blockIdx.x, tid = threadIdx.x;
  if (bid < 384){
    const int z = bid%6, mt = (bid/6)%16, nt2 = bid/96;
    const int m0 = mt*128, n0 = nt2*128;
    const int wv = tid>>6, lane = tid&63;
    const int wm = wv>>1, wn = wv&1;
    const int r16 = lane&15, krow = lane>>4;
    f32x4 acc[4][4] = {};
    const unsigned short* Bh = WTH + (long)z*262144;
    const unsigned short* Bl = WTL + (long)z*262144;

    for (int k0 = 0; k0 < 512; k0 += 32){
      #pragma unroll
      for (int i=0; i<2; ++i){
        const int idx = i*256 + tid;
        const int row = idx >> 2, k8 = (idx & 3)*8;
        gload16(&V1H[(long)(m0+row)*512 + k0 + k8], (char*)AH + i*4096 + wv*1024);
        gload16(&V1L[(long)(m0+row)*512 + k0 + k8], (char*)AL + i*4096 + wv*1024);
        gload16(&Bh [(long)(n0+row)*512 + k0 + k8], (char*)BH + i*4096 + wv*1024);
        gload16(&Bl [(long)(n0+row)*512 + k0 + k8], (char*)BL + i*4096 + wv*1024);
      }
      __syncthreads();
      short8 ah[4], al[4], bh[4], bl[4];
      #pragma unroll
      for (int mi=0; mi<4; ++mi){
        const int off = (wm*64 + mi*16 + r16)*32 + krow*8;
        ah[mi] = *(const short8*)&AH[off];
        al[mi] = *(const short8*)&AL[off];
      }
      #pragma unroll
      for (int ni=0; ni<4; ++ni){
        const int off = (wn*64 + ni*16 + r16)*32 + krow*8;
        bh[ni] = *(const short8*)&BH[off];
        bl[ni] = *(const short8*)&BL[off];
      }
      #pragma unroll
      for (int mi=0; mi<4; ++mi)
        #pragma unroll
        for (int ni=0; ni<4; ++ni){
          acc[mi][ni] = __builtin_amdgcn_mfma_f32_16x16x32_bf16(ah[mi], bh[ni], acc[mi][ni], 0, 0, 0);
          acc[mi][ni] = __builtin_amdgcn_mfma_f32_16x16x32_bf16(ah[mi], bl[ni], acc[mi][ni], 0, 0, 0);
          acc[mi][ni] = __builtin_amdgcn_mfma_f32_16x16x32_bf16(al[mi], bh[ni], acc[mi][ni], 0, 0, 0);
        }
      __syncthreads();
    }
    #pragma unroll
    for (int ni=0; ni<4; ++ni){
      const int col = n0 + wn*64 + ni*16 + r16;
      #pragma unroll
      for (int mi=0; mi<4; ++mi){
        const int rbase = m0 + wm*64 + mi*16 + krow*4;
        #pragma unroll
        for (int j=0; j<4; ++j)
          Ub[(long)(rbase + j)*3072 + z*512 + col] = acc[mi][ni][j];
      }
    }
  } else {
    const long n4 = (long)NTOKC*NHIDC/4;
    for (long i = (long)(bid-384)*256 + tid; i < n4; i += (long)384*256){
      const float4 v = ((const float4*)Wd)[i];
      ushort4 o;
      __hip_bfloat16 b0 = __float2bfloat16(v.x); o.x = *reinterpret_cast<unsigned short*>(&b0);
      __hip_bfloat16 b1 = __float2bfloat16(v.y); o.y = *reinterpret_cast<unsigned short*>(&b1);
      __hip_bfloat16 b2 = __float2bfloat16(v.z); o.z = *reinterpret_cast<unsigned short*>(&b2);
      __hip_bfloat16 b3 = __float2bfloat16(v.w); o.w = *reinterpret_cast<unsigned short*>(&b3);
      ((ushort4*)Wdb)[i] = o;
    }
  }
}

// ---------------- persistent recurrent kernel (R16-proven: spread mapping, MALL tags) ----------------
__global__ __launch_bounds__(1024, 2) void recurrent_kernel(
    const float* __restrict__ hx0, const float* __restrict__ cx0,
    const float* __restrict__ Wq_in, const float* __restrict__ Whh,
    const float* __restrict__ b_lstm,
    const float* __restrict__ Wk_c, const float* __restrict__ Wv_c,
    const float* __restrict__ Wq_c, const float* __restrict__ Wo_c,
    const float* __restrict__ K1buf, const float* __restrict__ Ubuf,
    u64* __restrict__ xpub,
    unsigned short* __restrict__ HTx,
    float* __restrict__ out_hx, float* __restrict__ out_cx)
{
  const int w = blockIdx.x, gg = w/6, n = w - gg*6, tid = threadIdx.x;

  __shared__ float WcT[192*130];
  __shared__ float WqL[128*65];
  __shared__ float hL[2][128], cL[2][128], h0L[2][128], cnL[2][128];
  __shared__ float partL[2][2][512];
  __shared__ float uL[2][512];
  __shared__ float blL[512];
  __shared__ float kvqL[2][192];
  __shared__ float kvAll[2][6][130];
  __shared__ float commL[2][64];
  __shared__ float nullAll[2][8];
  __shared__ float sL[2], nullLoc[2], maskL[2];

  const int kh = tid >> 9, gc = tid & 511;
  const int od = tid >> 3, okq = tid & 7;

  f32x4 whr[16];
  {
    const float* src = Whh + (long)n*65536 + kh*64*512 + gc;
    #pragma unroll
    for (int r4=0; r4<16; ++r4){
      f32x4 v;
      v[0] = src[(r4*4+0)*512]; v[1] = src[(r4*4+1)*512];
      v[2] = src[(r4*4+2)*512]; v[3] = src[(r4*4+3)*512];
      whr[r4] = v;
    }
  }
  #pragma unroll
  for (int i=0;i<16;++i) asm volatile("" : "+v"(whr[i]));
  f32x4 wo0, wo1;
  {
    const float* src = Wo_c + n*8192 + od;
    #pragma unroll
    for (int j=0;j<4;++j) wo0[j] = src[(okq*8+j)*128];
    #pragma unroll
    for (int j=0;j<4;++j) wo1[j] = src[(okq*8+4+j)*128];
  }
  asm volatile("" : "+v"(wo0));
  asm volatile("" : "+v"(wo1));

  if (tid < 512) blL[tid] = b_lstm[n*512 + tid];
  for (int i = tid; i < 8192; i += 1024){
    const int h = i>>6, c = i&63;
    WcT[(c    )*130 + h] = Wk_c[n*8192 + i];
    WcT[(c+ 64)*130 + h] = Wv_c[n*8192 + i];
    WcT[(c+128)*130 + h] = Wq_c[n*8192 + i];
    WqL[h*65 + c] = Wq_in[n*8192 + i];
  }
  if (tid < 256){
    const int b = tid>>7, d = tid&127;
    hL[b][d] = hx0[(gg*2+b)*768 + n*128 + d];
    cL[b][d] = cx0[(gg*2+b)*768 + n*128 + d];
  }
  __syncthreads();

  for (int t = 0; t < TT; ++t){
    const int par = t & 1;
    const unsigned tag = (unsigned)(t+1);
    uL[kh][gc] = Ubuf[((long)(t*32 + gg*2 + kh)*6 + n)*512 + gc];
    float k1r = 0.f;
    if (tid < 128) k1r = K1buf[(long)(t*32 + gg*2 + (tid>>6))*64 + (tid&63)];

    // A: gate partials
    {
      float gd0 = 0.f, gd1 = 0.f;
      #pragma unroll
      for (int r4 = 0; r4 < 16; ++r4){
        const f32x4 h0v = *(const f32x4*)&hL[0][kh*64 + r4*4];
        const f32x4 h1v = *(const f32x4*)&hL[1][kh*64 + r4*4];
        #pragma unroll
        for (int j=0;j<4;++j){
          gd0 += whr[r4][j]*h0v[j];
          gd1 += whr[r4][j]*h1v[j];
        }
      }
      partL[0][kh][gc] = gd0;
      partL[1][kh][gc] = gd1;
    }
    // B: q1 + input-softmax s; publish tagged null
    if (tid < 128){
      const int b = tid>>6, k = tid&63;
      float q = 0.f;
      #pragma unroll 16
      for (int h=0; h<128; ++h) q += WqL[h*65 + k]*hL[b][h];
      float term = q*k1r;
      #pragma unroll
      for (int off=32; off; off>>=1) term += __shfl_xor(term, off);
      if (k == 0){
        const float l1 = term*0.125f;
        const float mx = fmaxf(l1, 0.f);
        const float e0 = expf(0.f-mx), e1 = expf(l1-mx);
        const float inv = 1.f/(e0+e1);
        sL[b] = e1*inv;
        nullLoc[b] = e0*inv;
        stp(xpub + xslot(par,gg,n,b) + 128, e0*inv, tag);
      }
    }
    __syncthreads();                                     // bar1
    // F: fused gate-combine + pointwise LSTM
    if (tid < 256){
      const int b = tid>>7, dd = tid&127;
      const float s = sL[b];
      const float gi = partL[b][0][dd]     + partL[b][1][dd]     + s*uL[b][dd]     + blL[dd];
      const float gf = partL[b][0][128+dd] + partL[b][1][128+dd] + s*uL[b][128+dd] + blL[128+dd];
      const float gG = partL[b][0][256+dd] + partL[b][1][256+dd] + s*uL[b][256+dd] + blL[256+dd];
      const float go = partL[b][0][384+dd] + partL[b][1][384+dd] + s*uL[b][384+dd] + blL[384+dd];
      const float cp = cL[b][dd];
      const float cn = sigf(gf)*cp + sigf(gi)*tanhf(gG);
      const float h0 = sigf(go)*tanhf(cn);
      cnL[b][dd] = cn; h0L[b][dd] = h0;
    }
    __syncthreads();                                     // bar2
    // H: kvq + inline tagged publish of k2/v2
    if (tid < 384){
      const int b = tid/192, c = tid%192;
      float a = 0.f;
      #pragma unroll
      for (int h4=0; h4<32; ++h4){
        const f32x2 wa = *(const f32x2*)&WcT[c*130 + h4*4];
        const f32x2 wb = *(const f32x2*)&WcT[c*130 + h4*4 + 2];
        const f32x4 hv = *(const f32x4*)&h0L[b][h4*4];
        a += wa[0]*hv[0] + wa[1]*hv[1] + wb[0]*hv[2] + wb[1]*hv[3];
      }
      kvqL[b][c] = a;
      if (c < 128) stp(xpub + xslot(par,gg,n,b) + c, a, tag);
    }
    __syncthreads();                                     // bar3
    // L: gather peers' k2/v2 + nulls (poll tagged data)
    for (int idx = tid; idx < 1536; idx += 1024){
      const int j = idx/256, r = idx&255, b = r>>7, c = r&127;
      if (j == n) kvAll[b][j][c] = kvqL[b][c];
      else        kvAll[b][j][c] = ldp(xpub + xslot(par,gg,j,b) + c, tag);
    }
    if (tid < 12){
      const int j = tid>>1, b = tid&1;
      if (j == n) nullAll[b][j] = nullLoc[b];
      else        nullAll[b][j] = ldp(xpub + xslot(par,gg,j,b) + 128, tag);
    }
    __syncthreads(); CBAR;                               // bar4
    // ATT: single wave
    if (tid < 64){
      const int lane = tid;
      const int g5 = lane>>3, l3 = lane&7;
      const int b = g5>>2, h = g5&3;
      float lg = -1e30f;
      if (l3 < 6){
        float s = 0.f;
        #pragma unroll
        for (int kk=0; kk<16; ++kk)
          s += kvqL[b][128 + h*16 + kk]*kvAll[b][l3][h*16 + kk];
        lg = s*0.25f;
      }
      float mx = lg;
      mx = fmaxf(mx, __shfl_xor(mx,1));
      mx = fmaxf(mx, __shfl_xor(mx,2));
      mx = fmaxf(mx, __shfl_xor(mx,4));
      float ev = (l3 < 6) ? expf(lg - mx) : 0.f;
      float sum = ev;
      sum += __shfl_xor(sum,1); sum += __shfl_xor(sum,2); sum += __shfl_xor(sum,4);
      const float myw = ev/sum;
      float s0 = 0.f, s1 = 0.f;
      #pragma unroll
      for (int j=0;j<6;++j){
        const float wj = __shfl(myw, g5*8 + j);
        s0 += wj*kvAll[b][j][64 + h*16 + l3*2];
        s1 += wj*kvAll[b][j][64 + h*16 + l3*2 + 1];
      }
      commL[b][h*16 + l3*2]     = s0;
      commL[b][h*16 + l3*2 + 1] = s1;
      if (lane < 2){
        const float own = nullAll[lane][n];
        int rank = 0;
        #pragma unroll
        for (int j=0;j<6;++j){
          const float v = nullAll[lane][j];
          rank += (v > own || (v == own && j < n)) ? 1 : 0;
        }
        maskL[lane] = (rank < 2) ? 0.f : 1.f;
      }
    }
    __syncthreads();                                     // bar5
    // Q: Wo-reduce + masked state commit
    {
      #pragma unroll
      for (int b=0; b<2; ++b){
        float a = 0.f;
        #pragma unroll
        for (int j=0;j<4;++j) a += commL[b][okq*8+j]*wo0[j];
        #pragma unroll
        for (int j=0;j<4;++j) a += commL[b][okq*8+4+j]*wo1[j];
        a += __shfl_xor(a,1); a += __shfl_xor(a,2); a += __shfl_xor(a,4);
        if (okq == 0 && maskL[b] != 0.f){
          hL[b][od] = h0L[b][od] + a;
          cL[b][od] = cnL[b][od];
        }
      }
    }
    __syncthreads();                                     // bar6
    // R: HT (bf16) + final outputs
    if (tid < 256){
      const int b = tid>>7, d = tid&127;
      const float hv = hL[b][d];
      __hip_bfloat16 hb16 = __float2bfloat16(hv);
      HTx[(long)(t*32 + gg*2 + b)*768 + n*128 + d] = *reinterpret_cast<unsigned short*>(&hb16);
      if (t == TT-1){
        out_hx[(gg*2+b)*768 + n*128 + d] = hv;
        out_cx[(gg*2+b)*768 + n*128 + d] = cL[b][d];
      }
    }
  }
}

// ---------------- decoder: K64, swizzled staging, LDS-staged coalesced epilogue ----------------
__global__ __launch_bounds__(256) void decoder_kernel(
    const unsigned short* __restrict__ A,   // [2048][768] bf16
    const unsigned short* __restrict__ Bw,  // [32000][768] bf16
    const float* __restrict__ bd,
    float* __restrict__ out)
{
  __shared__ union {
    struct { unsigned short As[8192]; unsigned short Bs[8192]; } k;  // [128][64] each
    float Cs[64*132];                                                // epilogue half-tile
  } sm;
  const int bid = blockIdx.x;
  const int tile = (bid & 7)*500 + (bid >> 3);
  const int m0 = (tile & 15)*128, n0 = (tile >> 4)*128;
  const int tid = threadIdx.x;
  const int wv = tid >> 6, lane = tid & 63;
  const int wm = wv >> 1, wn = wv & 1;
  const int r16 = lane & 15, krow = lane >> 4;

  f32x4 acc[4][4] = {};

  for (int k0 = 0; k0 < 768; k0 += 64){
    #pragma unroll
    for (int i=0; i<4; ++i){
      const int idx = i*256 + tid;
      const int row = idx >> 3, cp = idx & 7;          // dest chunk position
      const int csrc = cp ^ (row & 7);                 // pre-swizzled source chunk
      gload16(&A [(long)(m0+row)*768 + k0 + csrc*8], (char*)sm.k.As + i*4096 + wv*1024);
      gload16(&Bw[(long)(n0+row)*768 + k0 + csrc*8], (char*)sm.k.Bs + i*4096 + wv*1024);
    }
    __syncthreads();
    short8 af[4][2], bf[4][2];
    #pragma unroll
    for (int mi=0; mi<4; ++mi){
      const int row = wm*64 + mi*16 + r16;
      #pragma unroll
      for (int ks=0; ks<2; ++ks){
        const int kc = ks*4 + krow;
        af[mi][ks] = *(const short8*)&sm.k.As[row*64 + ((kc ^ (row&7))<<3)];
      }
    }
    #pragma unroll
    for (int ni=0; ni<4; ++ni){
      const int row = wn*64 + ni*16 + r16;
      #pragma unroll
      for (int ks=0; ks<2; ++ks){
        const int kc = ks*4 + krow;
        bf[ni][ks] = *(const short8*)&sm.k.Bs[row*64 + ((kc ^ (row&7))<<3)];
      }
    }
    #pragma unroll
    for (int mi=0; mi<4; ++mi)
      #pragma unroll
      for (int ni=0; ni<4; ++ni){
        acc[mi][ni] = __builtin_amdgcn_mfma_f32_16x16x32_bf16(af[mi][0], bf[ni][0], acc[mi][ni], 0, 0, 0);
        acc[mi][ni] = __builtin_amdgcn_mfma_f32_16x16x32_bf16(af[mi][1], bf[ni][1], acc[mi][ni], 0, 0, 0);
      }
    __syncthreads();
  }

  // epilogue: stage 64-row halves in LDS, write fully-coalesced 512B rows
  #pragma unroll
  for (int half = 0; half < 2; ++half){
    if (wm == half){
      #pragma unroll
      for (int ni=0; ni<4; ++ni){
        const int colL = wn*64 + ni*16 + r16;
        const float bv = bd[n0 + colL];
        #pragma unroll
        for (int mi=0; mi<4; ++mi){
          const int rL = mi*16 + krow*4;
          #pragma unroll
          for (int j=0; j<4; ++j)
            sm.Cs[(rL+j)*132 + colL] = acc[mi][ni][j] + bv;
        }
      }
    }
    __syncthreads();
    #pragma unroll
    for (int pass=0; pass<8; ++pass){
      const int idx = pass*256 + tid;               // float4 index
      const int r = idx >> 5, c4 = (idx & 31)*4;
      const float4 v = *(const float4*)&sm.Cs[r*132 + c4];
      *(float4*)&out[(size_t)(m0 + half*64 + r)*NTOKC + n0 + c4] = v;
    }
    __syncthreads();
  }
}

// ---------------- launch ----------------
extern "C" void kernel_launch(void* const* d_in, const int* in_sizes, int n_in,
                              void* d_out, int out_size, void* d_ws, size_t ws_size,
                              hipStream_t stream)
{
  (void)in_sizes; (void)n_in; (void)out_size; (void)ws_size;
  const float* x      = (const float*)d_in[0];
  const float* hx0    = (const float*)d_in[1];
  const float* cx0    = (const float*)d_in[2];
  const float* Wq_in  = (const float*)d_in[3];
  const float* Wk_in  = (const float*)d_in[4];
  const float* Wv_in  = (const float*)d_in[5];
  const float* Wih    = (const float*)d_in[6];
  const float* Whh    = (const float*)d_in[7];
  const float* b_lstm = (const float*)d_in[8];
  const float* Wq_c   = (const float*)d_in[9];
  const float* Wk_c   = (const float*)d_in[10];
  const float* Wv_c   = (const float*)d_in[11];
  const float* Wo_c   = (const float*)d_in[12];
  const float* Wd     = (const float*)d_in[13];
  const float* bd     = (const float*)d_in[14];

  char* ws = (char*)d_ws;
  u64*           xpub = (u64*)(ws + OFF_XPUB);
  unsigned short* WTH = (unsigned short*)(ws + OFF_WTH);
  unsigned short* WTL = (unsigned short*)(ws + OFF_WTL);
  unsigned short* HTx = (unsigned short*)(ws + OFF_HTB);
  float*         K1b  = (float*)(ws + OFF_K1);
  unsigned short* V1H = (unsigned short*)(ws + OFF_V1H);
  unsigned short* V1L = (unsigned short*)(ws + OFF_V1L);
  float*         Ub   = (float*)(ws + OFF_U);
  unsigned short* Wdb = (unsigned short*)(ws + OFF_WDB);

  float* out_dec = (float*)d_out;
  float* out_hx  = out_dec + (size_t)2048*NTOKC;
  float* out_cx  = out_hx + BB*NHIDC;

  // 1) K1 || V1(hi/lo) || xpub zero || WihT transpose (hi/lo)
  pre1_kernel<<<736, 256, 0, stream>>>(x, Wk_in, Wv_in, Wih, K1b,
                                       V1H, V1L, WTH, WTL, xpub);
  // 2) U via split-bf16 MFMA || Wd->bf16 cast
  pre2_kernel<<<768, 256, 0, stream>>>(V1H, V1L, WTH, WTL, Wd, Ub, Wdb);
  // 3) recurrence (R16-proven: spread mapping, MALL tagged exchange)
  recurrent_kernel<<<96, 1024, 0, stream>>>(hx0, cx0, Wq_in, Whh, b_lstm,
                                            Wk_c, Wv_c, Wq_c, Wo_c,
                                            K1b, Ub, xpub, HTx,
                                            out_hx, out_cx);
  // 4) decoder GEMM + bias (K64 swizzled staging, LDS-staged coalesced epilogue)
  decoder_kernel<<<4000, 256, 0, stream>>>(HTx, Wdb, bd, out_dec);
}

// Round 19
// 1127.034 us; speedup vs baseline: 1.0607x; 1.0607x over previous
//
#include <hip/hip_runtime.h>
#include <hip/hip_bf16.h>
#include <stdint.h>

// ---------------- constants ----------------
#define TT 64
#define BB 32
#define NHIDC 768
#define NBK 6
#define BSZ 128
#define NTOKC 32000

using f32x4  = __attribute__((ext_vector_type(4))) float;
using f32x2  = __attribute__((ext_vector_type(2))) float;
using short8 = __attribute__((ext_vector_type(8))) short;
typedef unsigned long long u64;

// ---------------- workspace layout (bytes) ----------------
#define OFF_XPUB  4096u        // [2][16][6][2][132] u64 tagged exchange
#define OFF_WTH   1048576u     // WihT hi bf16 [6][512][512] (3 MB)
#define OFF_WTL   4194304u     // WihT lo bf16 (3 MB)
#define OFF_HTB   8065024u     // [64][32][768] bf16
#define OFF_K1    11210752u    // [64][32][64] f32
#define OFF_V1H   11735040u    // V1 hi bf16 [2048][512] (2 MB)
#define OFF_V1L   13832192u    // V1 lo bf16 (2 MB)
#define OFF_U     15929344u    // [64][32][6][512] f32
#define OFF_WDB   41095168u    // [32000][768] bf16

__device__ __forceinline__ float sigf(float x){ return 1.f/(1.f + expf(-x)); }

// tagged 8B MALL-coherent exchange ops: tag in hi32, f32 value in lo32.
__device__ __forceinline__ void stp(u64* p, float v, unsigned tag){
  union { float f; unsigned u; } cv; cv.f = v;
  const u64 pk = ((u64)tag << 32) | cv.u;
  __hip_atomic_store(p, pk, __ATOMIC_RELAXED, __HIP_MEMORY_SCOPE_AGENT);
}
__device__ __forceinline__ float ldp(const u64* p, unsigned tag){
  u64 v = __hip_atomic_load(p, __ATOMIC_RELAXED, __HIP_MEMORY_SCOPE_AGENT);
  while ((unsigned)(v >> 32) < tag){
    __builtin_amdgcn_s_sleep(1);
    v = __hip_atomic_load(p, __ATOMIC_RELAXED, __HIP_MEMORY_SCOPE_AGENT);
  }
  union { unsigned u; float f; } cv; cv.u = (unsigned)v;
  return cv.f;
}
#define CBAR asm volatile("" ::: "memory")

__device__ __forceinline__ void gload16(const void* g, void* l){
  __builtin_amdgcn_global_load_lds(
      (const __attribute__((address_space(1))) unsigned int*)g,
      (__attribute__((address_space(3))) unsigned int*)l, 16, 0, 0);
}

__device__ __forceinline__ int xslot(int par, int gg, int nn, int b){
  return (((par*16 + gg)*6 + nn)*2 + b)*132;
}

__device__ __forceinline__ void split_hl(float v, unsigned short& h16, unsigned short& l16){
  __hip_bfloat16 h = __float2bfloat16(v);
  float hv = __bfloat162float(h);
  __hip_bfloat16 l = __float2bfloat16(v - hv);
  h16 = *reinterpret_cast<unsigned short*>(&h);
  l16 = *reinterpret_cast<unsigned short*>(&l);
}

// ---------------- shared 256-thread GEMM tile (f32 out, normal stores) ----------------
template<int TM, int TN>
__device__ void gemm_tile(const float* __restrict__ A, int lda,
                          const float* __restrict__ Bb, int ldb,
                          float* __restrict__ Cb, int ldc,
                          int N, int K, int m0, int n0,
                          float* AsP, float* BsP, int tid)
{
  constexpr int BM = 16*TM, BN = 16*TN;
  float (*As)[BM]   = reinterpret_cast<float(*)[BM]>(AsP);
  float (*Bs)[BN+4] = reinterpret_cast<float(*)[BN+4]>(BsP);
  const int tx = tid & 15, ty = tid >> 4;
  float acc[TM][TN];
  #pragma unroll
  for (int i=0;i<TM;++i)
    #pragma unroll
    for (int j=0;j<TN;++j) acc[i][j]=0.f;

  for (int k0=0; k0<K; k0+=16){
    {
      const int r = tid>>2, kk = (tid&3)*4;
      const float4 v0 = *(const float4*)&A[(long)(m0+r)*lda + k0 + kk];
      As[kk+0][r]=v0.x; As[kk+1][r]=v0.y; As[kk+2][r]=v0.z; As[kk+3][r]=v0.w;
    }
    {
      const int rb = tid>>4, cb = (tid&15)*4;
      float4 v0 = {0,0,0,0};
      if (n0+cb+4 <= N) v0 = *(const float4*)&Bb[(long)(k0+rb)*ldb + n0+cb];
      *(float4*)&Bs[rb][cb] = v0;
    }
    __syncthreads();
    #pragma unroll
    for (int kk=0; kk<16; ++kk){
      float av[TM], bv[TN];
      #pragma unroll
      for (int i=0;i<TM;++i) av[i] = As[kk][ty*TM+i];
      #pragma unroll
      for (int j=0;j<TN;++j) bv[j] = Bs[kk][tx*TN+j];
      #pragma unroll
      for (int i=0;i<TM;++i)
        #pragma unroll
        for (int j=0;j<TN;++j) acc[i][j] += av[i]*bv[j];
    }
    __syncthreads();
  }
  #pragma unroll
  for (int i=0;i<TM;++i){
    const int row = m0 + ty*TM + i;
    #pragma unroll
    for (int j=0;j<TN;++j){
      const int col = n0 + tx*TN + j;
      if (col < N) Cb[(long)row*ldc + col] = acc[i][j];
    }
  }
}

// ---------------- V1 GEMM tile with hi/lo bf16 epilogue (TM=TN=4) ----------------
__device__ void gemm_tile_v1(const float* __restrict__ A,
                             const float* __restrict__ Bb,
                             unsigned short* __restrict__ V1H,
                             unsigned short* __restrict__ V1L,
                             int m0, int n0,
                             float* AsP, float* BsP, int tid)
{
  float (*As)[64] = reinterpret_cast<float(*)[64]>(AsP);
  float (*Bs)[68] = reinterpret_cast<float(*)[68]>(BsP);
  const int tx = tid & 15, ty = tid >> 4;
  float acc[4][4];
  #pragma unroll
  for (int i=0;i<4;++i)
    #pragma unroll
    for (int j=0;j<4;++j) acc[i][j]=0.f;

  for (int k0=0; k0<768; k0+=16){
    {
      const int r = tid>>2, kk = (tid&3)*4;
      const float4 v0 = *(const float4*)&A[(long)(m0+r)*768 + k0 + kk];
      As[kk+0][r]=v0.x; As[kk+1][r]=v0.y; As[kk+2][r]=v0.z; As[kk+3][r]=v0.w;
    }
    {
      const int rb = tid>>4, cb = (tid&15)*4;
      const float4 v0 = *(const float4*)&Bb[(long)(k0+rb)*512 + n0+cb];
      *(float4*)&Bs[rb][cb] = v0;
    }
    __syncthreads();
    #pragma unroll
    for (int kk=0; kk<16; ++kk){
      float av[4], bv[4];
      #pragma unroll
      for (int i=0;i<4;++i) av[i] = As[kk][ty*4+i];
      #pragma unroll
      for (int j=0;j<4;++j) bv[j] = Bs[kk][tx*4+j];
      #pragma unroll
      for (int i=0;i<4;++i)
        #pragma unroll
        for (int j=0;j<4;++j) acc[i][j] += av[i]*bv[j];
    }
    __syncthreads();
  }
  #pragma unroll
  for (int i=0;i<4;++i){
    const int row = m0 + ty*4 + i;
    const int col0 = n0 + tx*4;
    ushort4 oh, ol;
    split_hl(acc[i][0], oh.x, ol.x);
    split_hl(acc[i][1], oh.y, ol.y);
    split_hl(acc[i][2], oh.z, ol.z);
    split_hl(acc[i][3], oh.w, ol.w);
    *(ushort4*)&V1H[(long)row*512 + col0] = oh;
    *(ushort4*)&V1L[(long)row*512 + col0] = ol;
  }
}

// ---------------- pre1: K1 || V1(hi/lo) || xpub zero || WihT transpose ----------------
__global__ __launch_bounds__(256) void pre1_kernel(
    const float* __restrict__ x,
    const float* __restrict__ Wk_in, const float* __restrict__ Wv_in,
    const float* __restrict__ Wih,
    float* __restrict__ K1b,
    unsigned short* __restrict__ V1H, unsigned short* __restrict__ V1L,
    unsigned short* __restrict__ WTH, unsigned short* __restrict__ WTL,
    u64* __restrict__ xpub)
{
  __shared__ float As[16*64];
  __shared__ float Bs[16*68];
  __shared__ float T[64][65];
  const int bid = blockIdx.x, tid = threadIdx.x;
  if (bid < 32){
    gemm_tile<4,4>(x, 768, Wk_in + 768*64, 64, K1b, 64, 64, 768,
                   bid*64, 0, As, Bs, tid);
  } else if (bid < 288){
    const int v = bid - 32;
    gemm_tile_v1(x, Wv_in + 768*512, V1H, V1L,
                 (v>>3)*64, (v&7)*64, As, Bs, tid);
  } else if (bid < 352){
    const int nx = 2*16*6*2*132;
    for (int i = (bid-288)*256 + tid; i < nx; i += 64*256)
      __hip_atomic_store(&xpub[i], 0ull, __ATOMIC_RELAXED, __HIP_MEMORY_SCOPE_AGENT);
  } else {
    // WihT[z][c][k] hi/lo: 64x64 LDS-tiled transpose, 384 blocks
    const int tb = bid - 352;
    const int z = tb>>6, tile = tb&63, kt = (tile>>3)<<6, ct = (tile&7)<<6;
    const float* src = Wih + (long)z*262144;
    #pragma unroll 4
    for (int i=0;i<16;++i){
      const int idx = i*256+tid, rr = idx>>6, cc = idx&63;
      T[rr][cc] = src[(long)(kt+rr)*512 + ct+cc];
    }
    __syncthreads();
    #pragma unroll 4
    for (int i=0;i<16;++i){
      const int idx = i*256+tid, cr = idx>>6, kk = idx&63;
      unsigned short h16, l16;
      split_hl(T[kk][cr], h16, l16);
      WTH[(long)z*262144 + (long)(ct+cr)*512 + kt+kk] = h16;
      WTL[(long)z*262144 + (long)(ct+cr)*512 + kt+kk] = l16;
    }
  }
}

// ---------------- pre2: U via split-bf16 MFMA (384 blocks) || Wd cast (384 blocks) ----------------
__global__ __launch_bounds__(256) void pre2_kernel(
    const unsigned short* __restrict__ V1H, const unsigned short* __restrict__ V1L,
    const unsigned short* __restrict__ WTH, const unsigned short* __restrict__ WTL,
    const float* __restrict__ Wd,
    float* __restrict__ Ub, unsigned short* __restrict__ Wdb)
{
  __shared__ unsigned short AH[4096], AL[4096], BH[4096], BL[4096];
  const int bid = blockIdx.x, tid = threadIdx.x;
  if (bid < 384){
    const int z = bid%6, mt = (bid/6)%16, nt2 = bid/96;
    const int m0 = mt*128, n0 = nt2*128;
    const int wv = tid>>6, lane = tid&63;
    const int wm = wv>>1, wn = wv&1;
    const int r16 = lane&15, krow = lane>>4;
    f32x4 acc[4][4] = {};
    const unsigned short* Bh = WTH + (long)z*262144;
    const unsigned short* Bl = WTL + (long)z*262144;

    for (int k0 = 0; k0 < 512; k0 += 32){
      #pragma unroll
      for (int i=0; i<2; ++i){
        const int idx = i*256 + tid;
        const int row = idx >> 2, k8 = (idx & 3)*8;
        gload16(&V1H[(long)(m0+row)*512 + k0 + k8], (char*)AH + i*4096 + wv*1024);
        gload16(&V1L[(long)(m0+row)*512 + k0 + k8], (char*)AL + i*4096 + wv*1024);
        gload16(&Bh [(long)(n0+row)*512 + k0 + k8], (char*)BH + i*4096 + wv*1024);
        gload16(&Bl [(long)(n0+row)*512 + k0 + k8], (char*)BL + i*4096 + wv*1024);
      }
      __syncthreads();
      short8 ah[4], al[4], bh[4], bl[4];
      #pragma unroll
      for (int mi=0; mi<4; ++mi){
        const int off = (wm*64 + mi*16 + r16)*32 + krow*8;
        ah[mi] = *(const short8*)&AH[off];
        al[mi] = *(const short8*)&AL[off];
      }
      #pragma unroll
      for (int ni=0; ni<4; ++ni){
        const int off = (wn*64 + ni*16 + r16)*32 + krow*8;
        bh[ni] = *(const short8*)&BH[off];
        bl[ni] = *(const short8*)&BL[off];
      }
      #pragma unroll
      for (int mi=0; mi<4; ++mi)
        #pragma unroll
        for (int ni=0; ni<4; ++ni){
          acc[mi][ni] = __builtin_amdgcn_mfma_f32_16x16x32_bf16(ah[mi], bh[ni], acc[mi][ni], 0, 0, 0);
          acc[mi][ni] = __builtin_amdgcn_mfma_f32_16x16x32_bf16(ah[mi], bl[ni], acc[mi][ni], 0, 0, 0);
          acc[mi][ni] = __builtin_amdgcn_mfma_f32_16x16x32_bf16(al[mi], bh[ni], acc[mi][ni], 0, 0, 0);
        }
      __syncthreads();
    }
    #pragma unroll
    for (int ni=0; ni<4; ++ni){
      const int col = n0 + wn*64 + ni*16 + r16;
      #pragma unroll
      for (int mi=0; mi<4; ++mi){
        const int rbase = m0 + wm*64 + mi*16 + krow*4;
        #pragma unroll
        for (int j=0; j<4; ++j)
          Ub[(long)(rbase + j)*3072 + z*512 + col] = acc[mi][ni][j];
      }
    }
  } else {
    const long n4 = (long)NTOKC*NHIDC/4;
    for (long i = (long)(bid-384)*256 + tid; i < n4; i += (long)384*256){
      const float4 v = ((const float4*)Wd)[i];
      ushort4 o;
      __hip_bfloat16 b0 = __float2bfloat16(v.x); o.x = *reinterpret_cast<unsigned short*>(&b0);
      __hip_bfloat16 b1 = __float2bfloat16(v.y); o.y = *reinterpret_cast<unsigned short*>(&b1);
      __hip_bfloat16 b2 = __float2bfloat16(v.z); o.z = *reinterpret_cast<unsigned short*>(&b2);
      __hip_bfloat16 b3 = __float2bfloat16(v.w); o.w = *reinterpret_cast<unsigned short*>(&b3);
      ((ushort4*)Wdb)[i] = o;
    }
  }
}

// ---------------- persistent recurrent kernel (R16-proven: spread mapping, MALL tags) ----------------
__global__ __launch_bounds__(1024, 2) void recurrent_kernel(
    const float* __restrict__ hx0, const float* __restrict__ cx0,
    const float* __restrict__ Wq_in, const float* __restrict__ Whh,
    const float* __restrict__ b_lstm,
    const float* __restrict__ Wk_c, const float* __restrict__ Wv_c,
    const float* __restrict__ Wq_c, const float* __restrict__ Wo_c,
    const float* __restrict__ K1buf, const float* __restrict__ Ubuf,
    u64* __restrict__ xpub,
    unsigned short* __restrict__ HTx,
    float* __restrict__ out_hx, float* __restrict__ out_cx)
{
  const int w = blockIdx.x, gg = w/6, n = w - gg*6, tid = threadIdx.x;

  __shared__ float WcT[192*130];
  __shared__ float WqL[128*65];
  __shared__ float hL[2][128], cL[2][128], h0L[2][128], cnL[2][128];
  __shared__ float partL[2][2][512];
  __shared__ float uL[2][512];
  __shared__ float blL[512];
  __shared__ float kvqL[2][192];
  __shared__ float kvAll[2][6][130];
  __shared__ float commL[2][64];
  __shared__ float nullAll[2][8];
  __shared__ float sL[2], nullLoc[2], maskL[2];

  const int kh = tid >> 9, gc = tid & 511;
  const int od = tid >> 3, okq = tid & 7;

  f32x4 whr[16];
  {
    const float* src = Whh + (long)n*65536 + kh*64*512 + gc;
    #pragma unroll
    for (int r4=0; r4<16; ++r4){
      f32x4 v;
      v[0] = src[(r4*4+0)*512]; v[1] = src[(r4*4+1)*512];
      v[2] = src[(r4*4+2)*512]; v[3] = src[(r4*4+3)*512];
      whr[r4] = v;
    }
  }
  #pragma unroll
  for (int i=0;i<16;++i) asm volatile("" : "+v"(whr[i]));
  f32x4 wo0, wo1;
  {
    const float* src = Wo_c + n*8192 + od;
    #pragma unroll
    for (int j=0;j<4;++j) wo0[j] = src[(okq*8+j)*128];
    #pragma unroll
    for (int j=0;j<4;++j) wo1[j] = src[(okq*8+4+j)*128];
  }
  asm volatile("" : "+v"(wo0));
  asm volatile("" : "+v"(wo1));

  if (tid < 512) blL[tid] = b_lstm[n*512 + tid];
  for (int i = tid; i < 8192; i += 1024){
    const int h = i>>6, c = i&63;
    WcT[(c    )*130 + h] = Wk_c[n*8192 + i];
    WcT[(c+ 64)*130 + h] = Wv_c[n*8192 + i];
    WcT[(c+128)*130 + h] = Wq_c[n*8192 + i];
    WqL[h*65 + c] = Wq_in[n*8192 + i];
  }
  if (tid < 256){
    const int b = tid>>7, d = tid&127;
    hL[b][d] = hx0[(gg*2+b)*768 + n*128 + d];
    cL[b][d] = cx0[(gg*2+b)*768 + n*128 + d];
  }
  __syncthreads();

  for (int t = 0; t < TT; ++t){
    const int par = t & 1;
    const unsigned tag = (unsigned)(t+1);
    uL[kh][gc] = Ubuf[((long)(t*32 + gg*2 + kh)*6 + n)*512 + gc];
    float k1r = 0.f;
    if (tid < 128) k1r = K1buf[(long)(t*32 + gg*2 + (tid>>6))*64 + (tid&63)];

    // A: gate partials
    {
      float gd0 = 0.f, gd1 = 0.f;
      #pragma unroll
      for (int r4 = 0; r4 < 16; ++r4){
        const f32x4 h0v = *(const f32x4*)&hL[0][kh*64 + r4*4];
        const f32x4 h1v = *(const f32x4*)&hL[1][kh*64 + r4*4];
        #pragma unroll
        for (int j=0;j<4;++j){
          gd0 += whr[r4][j]*h0v[j];
          gd1 += whr[r4][j]*h1v[j];
        }
      }
      partL[0][kh][gc] = gd0;
      partL[1][kh][gc] = gd1;
    }
    // B: q1 + input-softmax s; publish tagged null
    if (tid < 128){
      const int b = tid>>6, k = tid&63;
      float q = 0.f;
      #pragma unroll 16
      for (int h=0; h<128; ++h) q += WqL[h*65 + k]*hL[b][h];
      float term = q*k1r;
      #pragma unroll
      for (int off=32; off; off>>=1) term += __shfl_xor(term, off);
      if (k == 0){
        const float l1 = term*0.125f;
        const float mx = fmaxf(l1, 0.f);
        const float e0 = expf(0.f-mx), e1 = expf(l1-mx);
        const float inv = 1.f/(e0+e1);
        sL[b] = e1*inv;
        nullLoc[b] = e0*inv;
        stp(xpub + xslot(par,gg,n,b) + 128, e0*inv, tag);
      }
    }
    __syncthreads();                                     // bar1
    // F: fused gate-combine + pointwise LSTM
    if (tid < 256){
      const int b = tid>>7, dd = tid&127;
      const float s = sL[b];
      const float gi = partL[b][0][dd]     + partL[b][1][dd]     + s*uL[b][dd]     + blL[dd];
      const float gf = partL[b][0][128+dd] + partL[b][1][128+dd] + s*uL[b][128+dd] + blL[128+dd];
      const float gG = partL[b][0][256+dd] + partL[b][1][256+dd] + s*uL[b][256+dd] + blL[256+dd];
      const float go = partL[b][0][384+dd] + partL[b][1][384+dd] + s*uL[b][384+dd] + blL[384+dd];
      const float cp = cL[b][dd];
      const float cn = sigf(gf)*cp + sigf(gi)*tanhf(gG);
      const float h0 = sigf(go)*tanhf(cn);
      cnL[b][dd] = cn; h0L[b][dd] = h0;
    }
    __syncthreads();                                     // bar2
    // H: kvq + inline tagged publish of k2/v2
    if (tid < 384){
      const int b = tid/192, c = tid%192;
      float a = 0.f;
      #pragma unroll
      for (int h4=0; h4<32; ++h4){
        const f32x2 wa = *(const f32x2*)&WcT[c*130 + h4*4];
        const f32x2 wb = *(const f32x2*)&WcT[c*130 + h4*4 + 2];
        const f32x4 hv = *(const f32x4*)&h0L[b][h4*4];
        a += wa[0]*hv[0] + wa[1]*hv[1] + wb[0]*hv[2] + wb[1]*hv[3];
      }
      kvqL[b][c] = a;
      if (c < 128) stp(xpub + xslot(par,gg,n,b) + c, a, tag);
    }
    __syncthreads();                                     // bar3
    // L: gather peers' k2/v2 + nulls (poll tagged data)
    for (int idx = tid; idx < 1536; idx += 1024){
      const int j = idx/256, r = idx&255, b = r>>7, c = r&127;
      if (j == n) kvAll[b][j][c] = kvqL[b][c];
      else        kvAll[b][j][c] = ldp(xpub + xslot(par,gg,j,b) + c, tag);
    }
    if (tid < 12){
      const int j = tid>>1, b = tid&1;
      if (j == n) nullAll[b][j] = nullLoc[b];
      else        nullAll[b][j] = ldp(xpub + xslot(par,gg,j,b) + 128, tag);
    }
    __syncthreads(); CBAR;                               // bar4
    // ATT: single wave
    if (tid < 64){
      const int lane = tid;
      const int g5 = lane>>3, l3 = lane&7;
      const int b = g5>>2, h = g5&3;
      float lg = -1e30f;
      if (l3 < 6){
        float s = 0.f;
        #pragma unroll
        for (int kk=0; kk<16; ++kk)
          s += kvqL[b][128 + h*16 + kk]*kvAll[b][l3][h*16 + kk];
        lg = s*0.25f;
      }
      float mx = lg;
      mx = fmaxf(mx, __shfl_xor(mx,1));
      mx = fmaxf(mx, __shfl_xor(mx,2));
      mx = fmaxf(mx, __shfl_xor(mx,4));
      float ev = (l3 < 6) ? expf(lg - mx) : 0.f;
      float sum = ev;
      sum += __shfl_xor(sum,1); sum += __shfl_xor(sum,2); sum += __shfl_xor(sum,4);
      const float myw = ev/sum;
      float s0 = 0.f, s1 = 0.f;
      #pragma unroll
      for (int j=0;j<6;++j){
        const float wj = __shfl(myw, g5*8 + j);
        s0 += wj*kvAll[b][j][64 + h*16 + l3*2];
        s1 += wj*kvAll[b][j][64 + h*16 + l3*2 + 1];
      }
      commL[b][h*16 + l3*2]     = s0;
      commL[b][h*16 + l3*2 + 1] = s1;
      if (lane < 2){
        const float own = nullAll[lane][n];
        int rank = 0;
        #pragma unroll
        for (int j=0;j<6;++j){
          const float v = nullAll[lane][j];
          rank += (v > own || (v == own && j < n)) ? 1 : 0;
        }
        maskL[lane] = (rank < 2) ? 0.f : 1.f;
      }
    }
    __syncthreads();                                     // bar5
    // Q: Wo-reduce + masked state commit
    {
      #pragma unroll
      for (int b=0; b<2; ++b){
        float a = 0.f;
        #pragma unroll
        for (int j=0;j<4;++j) a += commL[b][okq*8+j]*wo0[j];
        #pragma unroll
        for (int j=0;j<4;++j) a += commL[b][okq*8+4+j]*wo1[j];
        a += __shfl_xor(a,1); a += __shfl_xor(a,2); a += __shfl_xor(a,4);
        if (okq == 0 && maskL[b] != 0.f){
          hL[b][od] = h0L[b][od] + a;
          cL[b][od] = cnL[b][od];
        }
      }
    }
    __syncthreads();                                     // bar6
    // R: HT (bf16) + final outputs
    if (tid < 256){
      const int b = tid>>7, d = tid&127;
      const float hv = hL[b][d];
      __hip_bfloat16 hb16 = __float2bfloat16(hv);
      HTx[(long)(t*32 + gg*2 + b)*768 + n*128 + d] = *reinterpret_cast<unsigned short*>(&hb16);
      if (t == TT-1){
        out_hx[(gg*2+b)*768 + n*128 + d] = hv;
        out_cx[(gg*2+b)*768 + n*128 + d] = cL[b][d];
      }
    }
  }
}

// ---------------- decoder: K-step 64, XOR-swizzled staging, XCD-swizzled grid ----------------
__global__ __launch_bounds__(256) void decoder_kernel(
    const unsigned short* __restrict__ A,   // [2048][768] bf16
    const unsigned short* __restrict__ Bw,  // [32000][768] bf16
    const float* __restrict__ bd,
    float* __restrict__ out)
{
  __shared__ unsigned short As[8192];  // [128][64]
  __shared__ unsigned short Bs[8192];
  const int bid = blockIdx.x;
  const int tile = (bid & 7)*500 + (bid >> 3);
  const int m0 = (tile & 15)*128, n0 = (tile >> 4)*128;
  const int tid = threadIdx.x;
  const int wv = tid >> 6, lane = tid & 63;
  const int wm = wv >> 1, wn = wv & 1;
  const int r16 = lane & 15, krow = lane >> 4;

  f32x4 acc[4][4] = {};

  for (int k0 = 0; k0 < 768; k0 += 64){
    #pragma unroll
    for (int i=0; i<4; ++i){
      const int idx = i*256 + tid;
      const int row = idx >> 3, cp = idx & 7;          // dest chunk position
      const int csrc = cp ^ (row & 7);                 // pre-swizzled source chunk
      gload16(&A [(long)(m0+row)*768 + k0 + csrc*8], (char*)As + i*4096 + wv*1024);
      gload16(&Bw[(long)(n0+row)*768 + k0 + csrc*8], (char*)Bs + i*4096 + wv*1024);
    }
    __syncthreads();
    short8 af[4][2], bf[4][2];
    #pragma unroll
    for (int mi=0; mi<4; ++mi){
      const int row = wm*64 + mi*16 + r16;
      #pragma unroll
      for (int ks=0; ks<2; ++ks){
        const int kc = ks*4 + krow;
        af[mi][ks] = *(const short8*)&As[row*64 + ((kc ^ (row&7))<<3)];
      }
    }
    #pragma unroll
    for (int ni=0; ni<4; ++ni){
      const int row = wn*64 + ni*16 + r16;
      #pragma unroll
      for (int ks=0; ks<2; ++ks){
        const int kc = ks*4 + krow;
        bf[ni][ks] = *(const short8*)&Bs[row*64 + ((kc ^ (row&7))<<3)];
      }
    }
    #pragma unroll
    for (int mi=0; mi<4; ++mi)
      #pragma unroll
      for (int ni=0; ni<4; ++ni){
        acc[mi][ni] = __builtin_amdgcn_mfma_f32_16x16x32_bf16(af[mi][0], bf[ni][0], acc[mi][ni], 0, 0, 0);
        acc[mi][ni] = __builtin_amdgcn_mfma_f32_16x16x32_bf16(af[mi][1], bf[ni][1], acc[mi][ni], 0, 0, 0);
      }
    __syncthreads();
  }

  #pragma unroll
  for (int ni=0; ni<4; ++ni){
    const int col = n0 + wn*64 + ni*16 + r16;
    const float bv = bd[col];
    #pragma unroll
    for (int mi=0; mi<4; ++mi){
      const int rbase = m0 + wm*64 + mi*16 + krow*4;
      #pragma unroll
      for (int j=0; j<4; ++j)
        out[(size_t)(rbase + j)*NTOKC + col] = acc[mi][ni][j] + bv;
    }
  }
}

// ---------------- launch ----------------
extern "C" void kernel_launch(void* const* d_in, const int* in_sizes, int n_in,
                              void* d_out, int out_size, void* d_ws, size_t ws_size,
                              hipStream_t stream)
{
  (void)in_sizes; (void)n_in; (void)out_size; (void)ws_size;
  const float* x      = (const float*)d_in[0];
  const float* hx0    = (const float*)d_in[1];
  const float* cx0    = (const float*)d_in[2];
  const float* Wq_in  = (const float*)d_in[3];
  const float* Wk_in  = (const float*)d_in[4];
  const float* Wv_in  = (const float*)d_in[5];
  const float* Wih    = (const float*)d_in[6];
  const float* Whh    = (const float*)d_in[7];
  const float* b_lstm = (const float*)d_in[8];
  const float* Wq_c   = (const float*)d_in[9];
  const float* Wk_c   = (const float*)d_in[10];
  const float* Wv_c   = (const float*)d_in[11];
  const float* Wo_c   = (const float*)d_in[12];
  const float* Wd     = (const float*)d_in[13];
  const float* bd     = (const float*)d_in[14];

  char* ws = (char*)d_ws;
  u64*           xpub = (u64*)(ws + OFF_XPUB);
  unsigned short* WTH = (unsigned short*)(ws + OFF_WTH);
  unsigned short* WTL = (unsigned short*)(ws + OFF_WTL);
  unsigned short* HTx = (unsigned short*)(ws + OFF_HTB);
  float*         K1b  = (float*)(ws + OFF_K1);
  unsigned short* V1H = (unsigned short*)(ws + OFF_V1H);
  unsigned short* V1L = (unsigned short*)(ws + OFF_V1L);
  float*         Ub   = (float*)(ws + OFF_U);
  unsigned short* Wdb = (unsigned short*)(ws + OFF_WDB);

  float* out_dec = (float*)d_out;
  float* out_hx  = out_dec + (size_t)2048*NTOKC;
  float* out_cx  = out_hx + BB*NHIDC;

  // 1) K1 || V1(hi/lo) || xpub zero || WihT transpose (hi/lo)
  pre1_kernel<<<736, 256, 0, stream>>>(x, Wk_in, Wv_in, Wih, K1b,
                                       V1H, V1L, WTH, WTL, xpub);
  // 2) U via split-bf16 MFMA || Wd->bf16 cast
  pre2_kernel<<<768, 256, 0, stream>>>(V1H, V1L, WTH, WTL, Wd, Ub, Wdb);
  // 3) recurrence (R16-proven: spread mapping, MALL tagged exchange)
  recurrent_kernel<<<96, 1024, 0, stream>>>(hx0, cx0, Wq_in, Whh, b_lstm,
                                            Wk_c, Wv_c, Wq_c, Wo_c,
                                            K1b, Ub, xpub, HTx,
                                            out_hx, out_cx);
  // 4) decoder GEMM + bias (K64 swizzled staging, XCD-swizzled grid)
  decoder_kernel<<<4000, 256, 0, stream>>>(HTx, Wdb, bd, out_dec);
}